// Round 10
// baseline (170.226 us; speedup 1.0000x reference)
//
#include <hip/hip_runtime.h>
#include <hip/hip_fp8.h>

#define N_IN 1024
#define N_OUT 1024
#define BATCHN 8192

typedef __attribute__((ext_vector_type(4))) int intx4;
typedef __attribute__((ext_vector_type(8))) int intx8;
typedef __attribute__((ext_vector_type(16))) float floatx16;

// HW packed fp8 e4m3 (OCP on gfx950) convert: (a,b) -> 2 bytes, RNE+sat.
__device__ __forceinline__ unsigned int pk4_e4m3(float a, float b, float c,
                                                 float d) {
  int w = __builtin_amdgcn_cvt_pk_fp8_f32(a, b, 0, false);   // bytes 0,1
  w = __builtin_amdgcn_cvt_pk_fp8_f32(c, d, w, true);        // bytes 2,3
  return (unsigned int)w;
}
// gelu ~= v * sigmoid(1.702 v) = v * rcp(1 + exp2(-2.4554 v)).
__device__ __forceinline__ float gelu_fast(float v) {
  float e = __builtin_amdgcn_exp2f(-2.4554443f * v);
  return v * __builtin_amdgcn_rcpf(1.0f + e);
}

#define ASYNC_CP16(gp, lp)                                                     \
  __builtin_amdgcn_global_load_lds(                                            \
      (const __attribute__((address_space(1))) unsigned int*)(gp),             \
      (__attribute__((address_space(3))) unsigned int*)(lp), 16, 0, 0)

// ---------------------------------------------------------------------------
// Kernel 1 (merged prep, 3136 blocks x 256 thr, high occupancy, no barriers):
//  blocks [0,2048):    x rows (4/block, 1/wave): gelu(x)*4 -> fp8 e4m3 into
//                      g8 in PER-(rowblock,kt) 2KB A-slices:
//                        g8[rb][kt][row 0..31][chunk p 0..3][16B],
//                        p = c ^ (row&3)  (bank-spread for post-DMA ds_read)
//                      so gemm_ln's per-kt A DMA is a LINEAR 2KB copy.
//                      Also per-row segment stats -> seg2g[row][9] float2.
//  blocks [2048,3072): W rows -> fp8 (x16), MFMA-native tiled layout (64KB
//                      per kc: [colgrp 0..31][sec][lane][16B]) so gemm_ln's
//                      per-kt B DMA is a LINEAR 64KB copy.
//  blocks [3072,3136): slopes/intercepts [:,0,:] gather-transpose.
// ---------------------------------------------------------------------------
__global__ __launch_bounds__(256) void prep_all(const float* __restrict__ x,
                                                unsigned char* __restrict__ g8,
                                                float2* __restrict__ seg2g,
                                                const float* __restrict__ W,
                                                unsigned char* __restrict__ Wb8,
                                                const float* __restrict__ slopes,
                                                const float* __restrict__ icpts,
                                                float* __restrict__ slt,
                                                float* __restrict__ ict) {
  const int b = blockIdx.x, t = threadIdx.x;
  if (b < BATCHN / 4) {
    const int lane = t & 63, w = t >> 6;
    const int r = b * 4 + w;  // global row
    const float* xr = x + (long)r * N_IN;
    unsigned int* g32 = (unsigned int*)g8;
    const int rb = r >> 5, rl = r & 31, sw3 = rl & 3;
    const unsigned int rowbase = ((unsigned int)rb << 13) + (rl << 4);  // dwords
    float cumx[8], totx = 0.f;
    unsigned int cnt[8];  // ballot+popc accumulate (wave-uniform)
#pragma unroll
    for (int s = 0; s < 8; ++s) { cnt[s] = 0u; cumx[s] = 0.f; }
#pragma unroll
    for (int jc = 0; jc < 4; ++jc) {
      float4 v4 = ((const float4*)xr)[lane + 64 * jc];
      float vs[4] = {v4.x, v4.y, v4.z, v4.w};
      float gs[4];
#pragma unroll
      for (int e = 0; e < 4; ++e) {
        float v = vs[e];
        gs[e] = gelu_fast(v) * 4.0f;  // x4 scale, undone by MX scale operand
        totx += v;
#pragma unroll
        for (int k = 0; k < 8; ++k) {
          bool m = v >= (-1.0f + (float)(k + 1) * (2.0f / 9.0f));
          cumx[k] += m ? v : 0.0f;
          cnt[k] += (unsigned int)__popcll(__ballot(m));
        }
      }
      const unsigned int pk = pk4_e4m3(gs[0], gs[1], gs[2], gs[3]);
      const int d = lane + 64 * jc;  // dword index within row (0..255)
      const int kt = d >> 4;         // K64 chunk 0..15
      const int c = (d >> 2) & 3;    // logical 16B chunk within slice row
      const int wd = d & 3;          // dword within chunk
      g32[rowbase + (kt << 9) + ((c ^ sw3) << 2) + wd] = pk;
    }
#pragma unroll
    for (int off = 32; off > 0; off >>= 1) {
      totx += __shfl_xor(totx, off);
#pragma unroll
      for (int s = 0; s < 8; ++s) cumx[s] += __shfl_xor(cumx[s], off);
    }
    if (lane == 0) {
      seg2g[r * 9 + 0] = make_float2(totx - cumx[0], (float)(1024 - (int)cnt[0]));
#pragma unroll
      for (int s = 1; s < 8; ++s)
        seg2g[r * 9 + s] = make_float2(cumx[s - 1] - cumx[s],
                                       (float)((int)cnt[s - 1] - (int)cnt[s]));
      seg2g[r * 9 + 8] = make_float2(cumx[7], (float)cnt[7]);
    }
  } else if (b < BATCHN / 4 + N_OUT) {
    const int o = b - BATCHN / 4;  // W row == GEMM col
    float4 v = ((const float4*)(W + o * N_IN))[t];
    unsigned int pk =
        pk4_e4m3(v.x * 16.0f, v.y * 16.0f, v.z * 16.0f, v.w * 16.0f);
    const int kc = t >> 4;        // K64 chunk
    const int lh = (t >> 3) & 1;  // k-half within K64
    const int sec = (t >> 2) & 1; // lo/hi 16B segment
    const int off = (t & 3) * 4;  // dword within 16B segment
    const int lane = lh * 32 + (o & 31);
    *(unsigned int*)(Wb8 + kc * 65536 + (o >> 5) * 2048 + sec * 1024 +
                     lane * 16 + off) = pk;
  } else {
    const int gb = b - (BATCHN / 4 + N_OUT);  // 0..63
    const int o = gb * 16 + (t >> 4);
    const int s = t & 15;
    if (s < 9) {
      slt[s * N_OUT + o] = slopes[(long)o * 9216 + s];  // slopes[o][0][s]
      ict[s * N_OUT + o] = icpts[(long)o * 9216 + s];
    }
  }
}

// ---------------------------------------------------------------------------
// Kernel 2: GEMM + epilogue. 256 blocks x 1024 threads (16 waves), 1 blk/CU.
// LDS 138.5 KB: 2 x 66KB ping-pong (B 64KB + A 2KB per K64 step) + epilogue
// scratch. The >80KB pool makes a second co-resident block IMPOSSIBLE, so
// the register allocator finally budgets 128 VGPR (R6-R9 it targeted a
// phantom 2-blocks/CU = 8 waves/SIMD and squeezed to 60-64 VGPR, serializing
// every load against its MFMA).
//   Per kt: [6x ds_read_b128 frags from buf(kt&1)] -> __syncthreads (drains
//   lgkm: everyone done reading; vmcnt(0): DMA kt+1 landed) -> issue DMA
//   kt+2 into buf(kt&1) -> 2x MFMA. Each DMA has a full MFMA+ds_read phase
//   (~1300 cy/CU) to cover L2 latency; operands live ~24 regs.
//   K-sweep rotated by CU-within-XCD to spread L2 line pressure.
//   Epilogue: + bias + rank-18 lin term, full-row LayerNorm via shfl +
//   cross-wave LDS partials, PReLU, nontemporal f32 stores.
// ---------------------------------------------------------------------------
__global__ __launch_bounds__(1024) void gemm_ln(
    const unsigned char* __restrict__ g8, const unsigned char* __restrict__ Wb8,
    const float* __restrict__ biases, const float* __restrict__ slt,
    const float* __restrict__ ict, const float* __restrict__ prelu_w,
    const float2* __restrict__ seg2g, float* __restrict__ out) {
  __shared__ unsigned char pool[2][67584];  // [B 64KB][A 2KB] x2 = 132KB
  __shared__ float2 seg2f[288];             // 32 rows x 9 (sx,sc)
  __shared__ float2 red[16][32];            // per-wave (sum,sumsq) partials
  __shared__ float2 rowstat[32];            // (mu, rstd)

  const int t = threadIdx.x;
  const int lane = t & 63, w = t >> 6;  // 16 waves
  const int l31 = lane & 31, lh = lane >> 5;
  const int r0 = blockIdx.x * 32;
  const int rot = (blockIdx.x >> 3) & 15;  // CU-within-XCD K rotation

#define STAGE(p, kte)                                                          \
  {                                                                            \
    const unsigned char* bsrc = Wb8 + (kte) * 65536;                           \
    _Pragma("unroll") for (int j = 0; j < 4; ++j) {                            \
      const int sg = t + 1024 * j;                                             \
      ASYNC_CP16(bsrc + sg * 16, &pool[p][sg * 16]);                           \
    }                                                                          \
    if (t < 128)                                                               \
      ASYNC_CP16(g8 + ((long)blockIdx.x << 15) + (kte) * 2048 + t * 16,        \
                 &pool[p][65536 + t * 16]);                                    \
  }
#define MFMA(AF, BF, C)                                                        \
  __builtin_amdgcn_mfma_scale_f32_32x32x64_f8f6f4(                             \
      AF, BF, C, 0, 0, 0, 0x7D7D7D7Du /*A 2^-2*/, 0, 0x7B7B7B7Bu /*B 2^-4*/)

  // ---- Prologue: stage kt=0,1 + seg stats ------------------------------
  STAGE(0, rot);
  STAGE(1, (rot + 1) & 15);
  if (t < 288) seg2f[t] = seg2g[r0 * 9 + t];
  __syncthreads();  // vmcnt(0): both slices resident

  // ---- K loop: LDS ping-pong, one barrier per K64 step -----------------
  const int nb = w * 64;
  floatx16 acc[2] = {};
  const int sw3 = l31 & 3;
#pragma unroll
  for (int kt = 0; kt < 16; ++kt) {
    const int p = kt & 1;
    intx8 aF, bf0, bf1;
    {  // A frag: row l31, chunks lh*2, lh*2+1 (stored at c^(row&3))
      const unsigned char* ab = &pool[p][65536] + l31 * 64;
      intx4 lo = *(const intx4*)(ab + (((lh * 2) ^ sw3) << 4));
      intx4 hi = *(const intx4*)(ab + (((lh * 2 + 1) ^ sw3) << 4));
      aF[0] = lo[0]; aF[1] = lo[1]; aF[2] = lo[2]; aF[3] = lo[3];
      aF[4] = hi[0]; aF[5] = hi[1]; aF[6] = hi[2]; aF[7] = hi[3];
    }
    {  // B frags: col-groups 2w, 2w+1
      const unsigned char* bp = &pool[p][(2 * w) * 2048] + lane * 16;
      intx4 lo = *(const intx4*)bp;
      intx4 hi = *(const intx4*)(bp + 1024);
      bf0[0] = lo[0]; bf0[1] = lo[1]; bf0[2] = lo[2]; bf0[3] = lo[3];
      bf0[4] = hi[0]; bf0[5] = hi[1]; bf0[6] = hi[2]; bf0[7] = hi[3];
      lo = *(const intx4*)(bp + 2048);
      hi = *(const intx4*)(bp + 3072);
      bf1[0] = lo[0]; bf1[1] = lo[1]; bf1[2] = lo[2]; bf1[3] = lo[3];
      bf1[4] = hi[0]; bf1[5] = hi[1]; bf1[6] = hi[2]; bf1[7] = hi[3];
    }
    __syncthreads();  // all reads of buf p done; DMA kt+1 landed
    if (kt < 14) STAGE(p, (kt + 2 + rot) & 15);  // overwrite buf p for kt+2
    __builtin_amdgcn_s_setprio(1);
    acc[0] = MFMA(aF, bf0, acc[0]);
    acc[1] = MFMA(aF, bf1, acc[1]);
    __builtin_amdgcn_s_setprio(0);
  }

  // ---- Epilogue: bias + lin + LayerNorm + PReLU ------------------------
  // C/D 32x32 layout: col = lane&31, row = (rg&3) + 8*(rg>>2) + 4*(lane>>5)
  float bb[2], cs[2][9], ci[2][9];
#pragma unroll
  for (int ni = 0; ni < 2; ++ni) {
    const int c = nb + ni * 32 + l31;
    bb[ni] = biases[c];
#pragma unroll
    for (int s = 0; s < 9; ++s) {
      cs[ni][s] = slt[s * N_OUT + c];
      ci[ni][s] = ict[s * N_OUT + c];
    }
  }

#pragma unroll
  for (int rg = 0; rg < 16; ++rg) {
    const int rl = (rg & 3) + 8 * (rg >> 2) + 4 * lh;
    float2 sp[9];
#pragma unroll
    for (int s = 0; s < 9; ++s) sp[s] = seg2f[rl * 9 + s];  // b64 broadcast
    float ssum = 0.f, qsum = 0.f;
#pragma unroll
    for (int ni = 0; ni < 2; ++ni) {
      float y = acc[ni][rg] + bb[ni];
#pragma unroll
      for (int s = 0; s < 9; ++s) y += sp[s].x * cs[ni][s] + sp[s].y * ci[ni][s];
      acc[ni][rg] = y;  // keep y in-register until mu/rstd known
      ssum += y;
      qsum += y * y;
    }
#pragma unroll
    for (int off = 16; off > 0; off >>= 1) {  // stays within 32-lane half
      ssum += __shfl_xor(ssum, off);
      qsum += __shfl_xor(qsum, off);
    }
    if (l31 == 0) red[w][rl] = make_float2(ssum, qsum);  // lanes 0 and 32
  }
  __syncthreads();
  if (t < 32) {
    float s = 0.f, q = 0.f;
#pragma unroll
    for (int wv = 0; wv < 16; ++wv) {
      float2 p = red[wv][t];
      s += p.x;
      q += p.y;
    }
    const float mu = s * (1.0f / 1024.0f);
    const float rstd = rsqrtf(q * (1.0f / 1024.0f) - mu * mu + 1e-5f);
    rowstat[t] = make_float2(mu, rstd);
  }
  const float pw = prelu_w[0];
  __syncthreads();
#pragma unroll
  for (int rg = 0; rg < 16; ++rg) {
    const int rl = (rg & 3) + 8 * (rg >> 2) + 4 * lh;
    const float2 ms = rowstat[rl];
    float* orow = out + (r0 + rl) * N_OUT;
#pragma unroll
    for (int ni = 0; ni < 2; ++ni) {
      float z = (acc[ni][rg] - ms.x) * ms.y;
      z = z >= 0.f ? z : pw * z;
      __builtin_nontemporal_store(z, &orow[nb + ni * 32 + l31]);
    }
  }
}

extern "C" void kernel_launch(void* const* d_in, const int* in_sizes, int n_in,
                              void* d_out, int out_size, void* d_ws, size_t ws_size,
                              hipStream_t stream) {
  const float* x = (const float*)d_in[0];
  const float* W = (const float*)d_in[1];
  const float* biases = (const float*)d_in[2];
  const float* slopes = (const float*)d_in[3];
  const float* icpts = (const float*)d_in[4];
  const float* prelu_w = (const float*)d_in[5];
  float* out = (float*)d_out;

  char* ws = (char*)d_ws;
  unsigned char* Wb8 = (unsigned char*)ws;               // 1 MB fp8 16*W (tiled)
  float* slt = (float*)(ws + (2u << 20));                // 9*1024 fp32
  float* ict = (float*)(ws + (2u << 20) + (64u << 10));  // 9*1024 fp32
  unsigned char* g8 = (unsigned char*)(ws + (4u << 20)); // 8 MB fp8, kt-tiled
  float2* seg2g = (float2*)(ws + (12u << 20));           // 8192*9 float2

  prep_all<<<BATCHN / 4 + N_OUT + 64, 256, 0, stream>>>(
      x, g8, seg2g, W, Wb8, slopes, icpts, slt, ict);
  gemm_ln<<<BATCHN / 32, 1024, 0, stream>>>(g8, Wb8, biases, slt, ict, prelu_w,
                                            seg2g, out);
}

// Round 11
// 163.530 us; speedup vs baseline: 1.0409x; 1.0409x over previous
//
#include <hip/hip_runtime.h>
#include <hip/hip_fp8.h>

#define N_IN 1024
#define N_OUT 1024
#define BATCHN 8192

typedef __attribute__((ext_vector_type(4))) int intx4;
typedef __attribute__((ext_vector_type(8))) int intx8;
typedef __attribute__((ext_vector_type(16))) float floatx16;

// HW packed fp8 e4m3 (OCP on gfx950) convert: (a,b) -> 2 bytes, RNE+sat.
__device__ __forceinline__ unsigned int pk4_e4m3(float a, float b, float c,
                                                 float d) {
  int w = __builtin_amdgcn_cvt_pk_fp8_f32(a, b, 0, false);   // bytes 0,1
  w = __builtin_amdgcn_cvt_pk_fp8_f32(c, d, w, true);        // bytes 2,3
  return (unsigned int)w;
}
// gelu ~= v * sigmoid(1.702 v) = v * rcp(1 + exp2(-2.4554 v)).
__device__ __forceinline__ float gelu_fast(float v) {
  float e = __builtin_amdgcn_exp2f(-2.4554443f * v);
  return v * __builtin_amdgcn_rcpf(1.0f + e);
}

#define ASYNC_CP16(gp, lp)                                                     \
  __builtin_amdgcn_global_load_lds(                                            \
      (const __attribute__((address_space(1))) unsigned int*)(gp),             \
      (__attribute__((address_space(3))) unsigned int*)(lp), 16, 0, 0)

// ---------------------------------------------------------------------------
// Kernel 1 (merged prep, 3136 blocks x 256 thr, high occupancy, no barriers):
//  blocks [0,2048):    x rows (4/block, 1/wave): gelu(x)*4 -> fp8 e4m3 into
//                      g8 with the 16B-chunk XOR swizzle (chunk pc of row r
//                      holds logical chunk pc^(r&7)) — the LDS image gemm_ln
//                      wants, so its global->LDS DMA is a LINEAR 32KB copy.
//                      Also per-row segment stats -> seg2g[row][9] float2.
//  blocks [2048,3072): W rows -> fp8 (x16), MFMA-native tiled layout (2KB
//                      per (kc,colgrp): [sec][lane][16B]) for coalesced
//                      B-fragment loads straight from L2.
//  blocks [3072,3136): slopes/intercepts [:,0,:] gather-transpose.
// ---------------------------------------------------------------------------
__global__ __launch_bounds__(256) void prep_all(const float* __restrict__ x,
                                                unsigned char* __restrict__ g8,
                                                float2* __restrict__ seg2g,
                                                const float* __restrict__ W,
                                                unsigned char* __restrict__ Wb8,
                                                const float* __restrict__ slopes,
                                                const float* __restrict__ icpts,
                                                float* __restrict__ slt,
                                                float* __restrict__ ict) {
  const int b = blockIdx.x, t = threadIdx.x;
  if (b < BATCHN / 4) {
    const int lane = t & 63, w = t >> 6;
    const int r = b * 4 + w;  // global row
    const float* xr = x + (long)r * N_IN;
    unsigned int* grow = (unsigned int*)(g8 + (long)r * N_IN);
    const int sw = r & 7;
    float cumx[8], totx = 0.f;
    unsigned int cnt[8];  // ballot+popc accumulate (wave-uniform)
#pragma unroll
    for (int s = 0; s < 8; ++s) { cnt[s] = 0u; cumx[s] = 0.f; }
#pragma unroll
    for (int jc = 0; jc < 4; ++jc) {
      float4 v4 = ((const float4*)xr)[lane + 64 * jc];
      float vs[4] = {v4.x, v4.y, v4.z, v4.w};
      float gs[4];
#pragma unroll
      for (int e = 0; e < 4; ++e) {
        float v = vs[e];
        gs[e] = gelu_fast(v) * 4.0f;  // x4 scale, undone by MX scale operand
        totx += v;
#pragma unroll
        for (int k = 0; k < 8; ++k) {
          bool m = v >= (-1.0f + (float)(k + 1) * (2.0f / 9.0f));
          cumx[k] += m ? v : 0.0f;
          cnt[k] += (unsigned int)__popcll(__ballot(m));
        }
      }
      const unsigned int pk = pk4_e4m3(gs[0], gs[1], gs[2], gs[3]);
      const int d = lane + 64 * jc;  // dword index within row (0..255)
      grow[(((d >> 2) ^ sw) << 2) | (d & 3)] = pk;
    }
#pragma unroll
    for (int off = 32; off > 0; off >>= 1) {
      totx += __shfl_xor(totx, off);
#pragma unroll
      for (int s = 0; s < 8; ++s) cumx[s] += __shfl_xor(cumx[s], off);
    }
    if (lane == 0) {
      seg2g[r * 9 + 0] = make_float2(totx - cumx[0], (float)(1024 - (int)cnt[0]));
#pragma unroll
      for (int s = 1; s < 8; ++s)
        seg2g[r * 9 + s] = make_float2(cumx[s - 1] - cumx[s],
                                       (float)((int)cnt[s - 1] - (int)cnt[s]));
      seg2g[r * 9 + 8] = make_float2(cumx[7], (float)cnt[7]);
    }
  } else if (b < BATCHN / 4 + N_OUT) {
    const int o = b - BATCHN / 4;  // W row == GEMM col
    float4 v = ((const float4*)(W + o * N_IN))[t];
    unsigned int pk =
        pk4_e4m3(v.x * 16.0f, v.y * 16.0f, v.z * 16.0f, v.w * 16.0f);
    const int kc = t >> 4;        // K64 chunk
    const int lh = (t >> 3) & 1;  // k-half within K64
    const int sec = (t >> 2) & 1; // lo/hi 16B segment
    const int off = (t & 3) * 4;  // dword within 16B segment
    const int lane = lh * 32 + (o & 31);
    *(unsigned int*)(Wb8 + kc * 65536 + (o >> 5) * 2048 + sec * 1024 +
                     lane * 16 + off) = pk;
  } else {
    const int gb = b - (BATCHN / 4 + N_OUT);  // 0..63
    const int o = gb * 16 + (t >> 4);
    const int s = t & 15;
    if (s < 9) {
      slt[s * N_OUT + o] = slopes[(long)o * 9216 + s];  // slopes[o][0][s]
      ict[s * N_OUT + o] = icpts[(long)o * 9216 + s];
    }
  }
}

// ---------------------------------------------------------------------------
// Kernel 2: GEMM + epilogue. 256 blocks x 1024 threads (16 waves), 1 blk/CU.
// lA is DELIBERATELY over-allocated to 88KB (32KB used): total LDS ~95KB
// > 80KB makes a second co-resident block impossible. LLVM's AMDGPU
// scheduler derives its VGPR cap from LDS-limited occupancy — at 39KB LDS
// it targeted 2 blocks/CU (8 waves/SIMD -> 64-VGPR cap), which serialized
// every B load against its MFMA (R6/R9) or spilled the ping-pong (R7/R8).
// At 1 block/CU the cap is 128 VGPR and the depth-1 pipeline fits.
//   Stage:  A tile (32 rows x 1024 fp8, pre-swizzled) via LINEAR
//           global_load_lds DMA; B prologue loads issued BEFORE the barrier.
//   GEMM:   depth-1 B reg ping-pong: every MFMA consumes B loaded one full
//           iteration earlier -> L2 latency off the critical path.
//           K-sweep rotated by CU-within-XCD to spread L2 line pressure.
//   Epi:    + bias + rank-18 lin term, full-row LayerNorm via shfl +
//           cross-wave LDS partials, PReLU, nontemporal f32 stores.
// ---------------------------------------------------------------------------
__global__ __launch_bounds__(1024)
__attribute__((amdgpu_waves_per_eu(4, 4))) void gemm_ln(
    const unsigned char* __restrict__ g8, const unsigned char* __restrict__ Wb8,
    const float* __restrict__ biases, const float* __restrict__ slt,
    const float* __restrict__ ict, const float* __restrict__ prelu_w,
    const float2* __restrict__ seg2g, float* __restrict__ out) {
  __shared__ unsigned char lA[90112];  // 88KB declared (32KB used): occupancy pin
  __shared__ float2 seg2f[288];        // 32 rows x 9 (sx,sc)
  __shared__ float2 red[16][32];       // per-wave (sum, sumsq) partials
  __shared__ float2 rowstat[32];       // (mu, rstd)

  const int t = threadIdx.x;
  const int lane = t & 63, w = t >> 6;  // 16 waves
  const int l31 = lane & 31, lh = lane >> 5;
  const int r0 = blockIdx.x * 32;

  const int nb = w * 64;
  const unsigned char* aRow = lA + l31 * 1024;
  const int asw = l31 & 7;
  const unsigned char* bBase = Wb8 + (w * 2) * 2048 + lane * 16;

#define LOAD_A(ko, AF)                                                         \
  {                                                                            \
    const int c0 = ((ko) >> 4) + lh * 2;                                       \
    intx4 lo = *(const intx4*)(aRow + ((c0 ^ asw) << 4));                      \
    intx4 hi = *(const intx4*)(aRow + (((c0 + 1) ^ asw) << 4));                \
    AF[0] = lo[0]; AF[1] = lo[1]; AF[2] = lo[2]; AF[3] = lo[3];                \
    AF[4] = hi[0]; AF[5] = hi[1]; AF[6] = hi[2]; AF[7] = hi[3];                \
  }
#define LOAD_B(kc, ni, BF)                                                     \
  {                                                                            \
    const unsigned char* bp = bBase + (kc) * 65536 + (ni) * 2048;              \
    intx4 lo = *(const intx4*)bp;                                              \
    intx4 hi = *(const intx4*)(bp + 1024);                                     \
    BF[0] = lo[0]; BF[1] = lo[1]; BF[2] = lo[2]; BF[3] = lo[3];                \
    BF[4] = hi[0]; BF[5] = hi[1]; BF[6] = hi[2]; BF[7] = hi[3];                \
  }
#define MFMA(AF, BF, C)                                                        \
  __builtin_amdgcn_mfma_scale_f32_32x32x64_f8f6f4(                             \
      AF, BF, C, 0, 0, 0, 0x7D7D7D7Du /*A 2^-2*/, 0, 0x7B7B7B7Bu /*B 2^-4*/)

  // ---- Stage: B prologue prefetch (regs, no LDS dep) + A-tile DMA ------
  const int rot = (blockIdx.x >> 3) & 15;  // CU-within-XCD, 16-way
  intx8 a0, a1, bA0, bA1, bB0, bB1;
  LOAD_B(rot, 0, bA0);
  LOAD_B(rot, 1, bA1);
#pragma unroll
  for (int j = 0; j < 2; ++j) {
    const int sg = t + 1024 * j;  // 16B slot 0..2047
    ASYNC_CP16(g8 + (long)r0 * 1024 + sg * 16, &lA[sg * 16]);
  }
  if (t < 288) seg2f[t] = seg2g[r0 * 9 + t];
  __syncthreads();  // drains vmcnt (DMA) + lgkm (seg writes)

  // ---- GEMM: depth-1 software pipeline, B double-buffered in regs ------
  floatx16 acc[2] = {};
#pragma unroll
  for (int j = 0; j < 16; j += 2) {
    const int k0 = (j + rot) & 15;
    const int k1 = (j + 1 + rot) & 15;
    const int k2 = (j + 2 + rot) & 15;
    LOAD_A(k0 * 64, a0);
    LOAD_B(k1, 0, bB0);  // prefetch next kt while consuming bA
    LOAD_B(k1, 1, bB1);
    __builtin_amdgcn_s_setprio(1);
    acc[0] = MFMA(a0, bA0, acc[0]);
    acc[1] = MFMA(a0, bA1, acc[1]);
    __builtin_amdgcn_s_setprio(0);
    LOAD_A(k1 * 64, a1);
    if (j < 14) {
      LOAD_B(k2, 0, bA0);  // prefetch kt+2 while consuming bB
      LOAD_B(k2, 1, bA1);
    }
    __builtin_amdgcn_s_setprio(1);
    acc[0] = MFMA(a1, bB0, acc[0]);
    acc[1] = MFMA(a1, bB1, acc[1]);
    __builtin_amdgcn_s_setprio(0);
  }

  // ---- Epilogue: bias + lin + LayerNorm + PReLU ------------------------
  // C/D 32x32 layout: col = lane&31, row = (rg&3) + 8*(rg>>2) + 4*(lane>>5)
  float bb[2], cs[2][9], ci[2][9];
#pragma unroll
  for (int ni = 0; ni < 2; ++ni) {
    const int c = nb + ni * 32 + l31;
    bb[ni] = biases[c];
#pragma unroll
    for (int s = 0; s < 9; ++s) {
      cs[ni][s] = slt[s * N_OUT + c];
      ci[ni][s] = ict[s * N_OUT + c];
    }
  }

#pragma unroll
  for (int rg = 0; rg < 16; ++rg) {
    const int rl = (rg & 3) + 8 * (rg >> 2) + 4 * lh;
    float2 sp[9];
#pragma unroll
    for (int s = 0; s < 9; ++s) sp[s] = seg2f[rl * 9 + s];  // b64 broadcast
    float ssum = 0.f, qsum = 0.f;
#pragma unroll
    for (int ni = 0; ni < 2; ++ni) {
      float y = acc[ni][rg] + bb[ni];
#pragma unroll
      for (int s = 0; s < 9; ++s) y += sp[s].x * cs[ni][s] + sp[s].y * ci[ni][s];
      acc[ni][rg] = y;  // keep y in-register until mu/rstd known
      ssum += y;
      qsum += y * y;
    }
#pragma unroll
    for (int off = 16; off > 0; off >>= 1) {  // stays within 32-lane half
      ssum += __shfl_xor(ssum, off);
      qsum += __shfl_xor(qsum, off);
    }
    if (l31 == 0) red[w][rl] = make_float2(ssum, qsum);  // lanes 0 and 32
  }
  __syncthreads();
  if (t < 32) {
    float s = 0.f, q = 0.f;
#pragma unroll
    for (int wv = 0; wv < 16; ++wv) {
      float2 p = red[wv][t];
      s += p.x;
      q += p.y;
    }
    const float mu = s * (1.0f / 1024.0f);
    const float rstd = rsqrtf(q * (1.0f / 1024.0f) - mu * mu + 1e-5f);
    rowstat[t] = make_float2(mu, rstd);
  }
  const float pw = prelu_w[0];
  __syncthreads();
#pragma unroll
  for (int rg = 0; rg < 16; ++rg) {
    const int rl = (rg & 3) + 8 * (rg >> 2) + 4 * lh;
    const float2 ms = rowstat[rl];
    float* orow = out + (r0 + rl) * N_OUT;
#pragma unroll
    for (int ni = 0; ni < 2; ++ni) {
      float z = (acc[ni][rg] - ms.x) * ms.y;
      z = z >= 0.f ? z : pw * z;
      __builtin_nontemporal_store(z, &orow[nb + ni * 32 + l31]);
    }
  }
}

extern "C" void kernel_launch(void* const* d_in, const int* in_sizes, int n_in,
                              void* d_out, int out_size, void* d_ws, size_t ws_size,
                              hipStream_t stream) {
  const float* x = (const float*)d_in[0];
  const float* W = (const float*)d_in[1];
  const float* biases = (const float*)d_in[2];
  const float* slopes = (const float*)d_in[3];
  const float* icpts = (const float*)d_in[4];
  const float* prelu_w = (const float*)d_in[5];
  float* out = (float*)d_out;

  char* ws = (char*)d_ws;
  unsigned char* Wb8 = (unsigned char*)ws;               // 1 MB fp8 16*W (tiled)
  float* slt = (float*)(ws + (2u << 20));                // 9*1024 fp32
  float* ict = (float*)(ws + (2u << 20) + (64u << 10));  // 9*1024 fp32
  unsigned char* g8 = (unsigned char*)(ws + (4u << 20)); // 8 MB fp8, swizzled
  float2* seg2g = (float2*)(ws + (12u << 20));           // 8192*9 float2

  prep_all<<<BATCHN / 4 + N_OUT + 64, 256, 0, stream>>>(
      x, g8, seg2g, W, Wb8, slopes, icpts, slt, ict);
  gemm_ln<<<BATCHN / 32, 1024, 0, stream>>>(g8, Wb8, biases, slt, ict, prelu_w,
                                            seg2g, out);
}